// Round 23
// baseline (245.468 us; speedup 1.0000x reference)
//
#include <hip/hip_runtime.h>
#include <hip/hip_bf16.h>

// Problem constants
#define BB   2
#define LL   2048
#define DD   2048
#define HH   16
#define KVH  4
#define HDD  128
#define RDD  64
#define MM   (BB*LL)   // 4096 rows of x

typedef __attribute__((ext_vector_type(4))) float f32x4;
typedef __attribute__((ext_vector_type(8))) short bf16x8;
typedef unsigned short u16;

static __device__ __forceinline__ u16 f2b(float f) {
  __hip_bfloat16 b = __float2bfloat16(f);
  return *(const u16*)&b;
}

// async global(16B/lane) -> LDS (wave-uniform base + lane*16)
static __device__ __forceinline__ void gload_lds16(const void* g, void* l) {
  __builtin_amdgcn_global_load_lds(
      (const __attribute__((address_space(1))) unsigned int*)g,
      (__attribute__((address_space(3))) unsigned int*)l, 16, 0, 0);
}

// log2(e)/sqrt(128): scores land in exp2 domain
#define QSCALE 0.1275174313f

// ---------------- all f32->bf16 casts in ONE kernel (5 segments) ----------------
// float4 counts: x 2,097,152 | Wq 1,048,576 | Wkv 262,144 | Wrk 32,768 | Wo 1,048,576
__global__ __launch_bounds__(256) void cast_all(const float* __restrict__ x,
                                                const float* __restrict__ Wq,
                                                const float* __restrict__ Wkv,
                                                const float* __restrict__ Wrk,
                                                const float* __restrict__ Wo,
                                                u16* __restrict__ xb, u16* __restrict__ Wqb,
                                                u16* __restrict__ Wkvb, u16* __restrict__ Wrkb,
                                                u16* __restrict__ Wob) {
  const int i = blockIdx.x * 256 + threadIdx.x;    // float4 index, total 4,489,216
  const float* src; u16* dst; int off;
  if (i < 2097152)      { src = x;   dst = xb;   off = i; }
  else if (i < 3145728) { src = Wq;  dst = Wqb;  off = i - 2097152; }
  else if (i < 3407872) { src = Wkv; dst = Wkvb; off = i - 3145728; }
  else if (i < 3440640) { src = Wrk; dst = Wrkb; off = i - 3407872; }
  else                  { src = Wo;  dst = Wob;  off = i - 3440640; }
  float4 v = ((const float4*)src)[off];
  ushort4 o;
  o.x = f2b(v.x); o.y = f2b(v.y); o.z = f2b(v.z); o.w = f2b(v.w);
  ((ushort4*)dst)[off] = o;
}

// ---------------- m97-style 128x128 tile GEMM (f32 out, for Wo) ----------------
__global__ __launch_bounds__(256) void gemm128(const u16* __restrict__ A,
                                               const u16* __restrict__ W,
                                               const float* __restrict__ bias,
                                               float* __restrict__ C,
                                               int M, int N, int K) {
  __shared__ u16 As[128 * 32];
  __shared__ u16 Bs[128 * 32];
  const int w = threadIdx.x >> 6, lane = threadIdx.x & 63;
  const int r = lane & 15, hi = lane >> 4, rg = hi * 4;
  const int wm = w >> 1, wn = w & 1;
  const int m0 = blockIdx.y * 128, n0 = blockIdx.x * 128;
  const int srow = w * 32 + (lane >> 2);
  const int scb  = (lane & 3) * 16;
  f32x4 acc[4][4];
#pragma unroll
  for (int i = 0; i < 4; ++i)
#pragma unroll
    for (int j = 0; j < 4; ++j) acc[i][j] = (f32x4){0.f, 0.f, 0.f, 0.f};

  for (int k0 = 0; k0 < K; k0 += 32) {
#pragma unroll
    for (int i = 0; i < 2; ++i) {
      gload_lds16((const char*)(A + (size_t)(m0 + srow + i * 16) * K + k0) + scb,
                  (char*)As + (w * 2 + i) * 1024);
      gload_lds16((const char*)(W + (size_t)(n0 + srow + i * 16) * K + k0) + scb,
                  (char*)Bs + (w * 2 + i) * 1024);
    }
    __syncthreads();
    bf16x8 a[4], b[4];
#pragma unroll
    for (int i = 0; i < 4; ++i)
      a[i] = *(const bf16x8*)((const char*)As + (wm * 64 + i * 16 + r) * 64 + hi * 16);
#pragma unroll
    for (int j = 0; j < 4; ++j)
      b[j] = *(const bf16x8*)((const char*)Bs + (wn * 64 + j * 16 + r) * 64 + hi * 16);
#pragma unroll
    for (int i = 0; i < 4; ++i)
#pragma unroll
      for (int j = 0; j < 4; ++j)
        acc[i][j] = __builtin_amdgcn_mfma_f32_16x16x32_bf16(a[i], b[j], acc[i][j], 0, 0, 0);
    __syncthreads();
  }
#pragma unroll
  for (int j = 0; j < 4; ++j) {
    const float bv = bias[n0 + wn * 64 + j * 16 + r];
#pragma unroll
    for (int i = 0; i < 4; ++i)
#pragma unroll
      for (int ii = 0; ii < 4; ++ii)
        C[(size_t)(m0 + wm * 64 + i * 16 + rg + ii) * N + n0 + wn * 64 + j * 16 + r] =
            acc[i][j][ii] + bv;
  }
}

// ---------------- unified projection kernel: q + kv + rk in ONE launch ----------------
// grid 1152 x 256. Block-uniform branch:
//   id in [0,512):    q GEMM block  (h = id&15, m-tile = id>>4)        -> Qb images
//   id in [512,640):  kv GEMM block (c = (id-512)&3, m-tile = (id-512)>>2) -> Kb/VTb images
//   id in [640,1152): rk block      (bx = (id-640)&1, m0 = ((id-640)>>1)*16) -> Kb d>=64
// All bodies byte-equivalent to the round-18-verified kernels; 16KB shared union.
__global__ __launch_bounds__(256) void proj_fused(const u16* __restrict__ xb,
                                                  const u16* __restrict__ Wqb,
                                                  const float* __restrict__ bq,
                                                  const u16* __restrict__ Wkvb,
                                                  const float* __restrict__ bkv,
                                                  const u16* __restrict__ Wrkb,
                                                  const float* __restrict__ brk,
                                                  const float* __restrict__ cosb,
                                                  const float* __restrict__ sinb,
                                                  u16* __restrict__ Qb,
                                                  u16* __restrict__ Kb,
                                                  u16* __restrict__ VTb) {
  __shared__ __align__(16) char SB[16384];
  const int id = blockIdx.x;
  const int w = threadIdx.x >> 6, lane = threadIdx.x & 63;
  const int r = lane & 15, hi = lane >> 4, rg = hi * 4;

  if (id < 640) {
    // ---------- 128x128 GEMM path (q or kv) ----------
    u16* As = (u16*)SB;                             // 8KB
    u16* Bs = (u16*)(SB + 8192);                    // 8KB
    const int wm = w >> 1, wn = w & 1;
    const bool isQ = (id < 512);
    int m0, n0, hc;
    const u16* W;
    const float* bias;
    if (isQ) { hc = id & 15; m0 = (id >> 4) * 128; n0 = hc * 128; W = Wqb; bias = bq; }
    else     { const int cid = id - 512; hc = cid & 3; m0 = (cid >> 2) * 128; n0 = hc * 128; W = Wkvb; bias = bkv; }
    const int srow = w * 32 + (lane >> 2);
    const int scb  = (lane & 3) * 16;
    f32x4 acc[4][4];
#pragma unroll
    for (int i = 0; i < 4; ++i)
#pragma unroll
      for (int j = 0; j < 4; ++j) acc[i][j] = (f32x4){0.f, 0.f, 0.f, 0.f};

    for (int k0 = 0; k0 < DD; k0 += 32) {
#pragma unroll
      for (int i = 0; i < 2; ++i) {
        gload_lds16((const char*)(xb + (size_t)(m0 + srow + i * 16) * DD + k0) + scb,
                    (char*)As + (w * 2 + i) * 1024);
        gload_lds16((const char*)(W + (size_t)(n0 + srow + i * 16) * DD + k0) + scb,
                    (char*)Bs + (w * 2 + i) * 1024);
      }
      __syncthreads();
      bf16x8 a[4], b[4];
#pragma unroll
      for (int i = 0; i < 4; ++i)
        a[i] = *(const bf16x8*)((const char*)As + (wm * 64 + i * 16 + r) * 64 + hi * 16);
#pragma unroll
      for (int j = 0; j < 4; ++j)
        b[j] = *(const bf16x8*)((const char*)Bs + (wn * 64 + j * 16 + r) * 64 + hi * 16);
#pragma unroll
      for (int i = 0; i < 4; ++i)
#pragma unroll
        for (int j = 0; j < 4; ++j)
          acc[i][j] = __builtin_amdgcn_mfma_f32_16x16x32_bf16(a[i], b[j], acc[i][j], 0, 0, 0);
      __syncthreads();
    }

    const int b = m0 >> 11;
    const int lbase = (m0 & 2047) + wm * 64;
    if (isQ) {
      const int h = hc;
      u16* Qimg = Qb + (size_t)((b * 16 + h) * 128) * 2048;
      if (wn == 0) {
#pragma unroll
        for (int j = 0; j < 4; ++j) {
          const int d = j * 16 + r;                 // < 64: no rope
          const float bv = bq[h * 128 + d];
#pragma unroll
          for (int i = 0; i < 4; ++i)
#pragma unroll
            for (int ii = 0; ii < 4; ++ii) {
              const int l = lbase + i * 16 + rg + ii;
              Qimg[(size_t)(l >> 4) * 2048 + (d >> 5) * 512 + ((d >> 3) & 3) * 128 +
                   (l & 15) * 8 + (d & 7)] = f2b((acc[i][j][ii] + bv) * QSCALE);
            }
        }
      } else {
#pragma unroll
        for (int jp = 0; jp < 2; ++jp) {
          const int dd0 = jp * 16 + r;              // 0..31
          const int dd1 = dd0 + 32;                 // 32..63
          const float bv0 = bq[h * 128 + 64 + dd0];
          const float bv1 = bq[h * 128 + 64 + dd1];
#pragma unroll
          for (int i = 0; i < 4; ++i)
#pragma unroll
            for (int ii = 0; ii < 4; ++ii) {
              const int l = lbase + i * 16 + rg + ii;
              const size_t nb = (size_t)(b * 2048 + l) * 64;
              const float c0 = cosb[nb + dd0], s0 = sinb[nb + dd0];
              const float c1 = cosb[nb + dd1], s1 = sinb[nb + dd1];
              const float a0 = acc[i][jp][ii] + bv0;
              const float a1 = acc[i][jp + 2][ii] + bv1;
              const float v0 = (a0 * c0 - a1 * s0) * QSCALE;
              const float v1 = (a1 * c1 + a0 * s1) * QSCALE;
              const int d0f = 64 + dd0, d1f = 64 + dd1;
              const size_t rowoff = (size_t)(l >> 4) * 2048 + (l & 15) * 8;
              Qimg[rowoff + (d0f >> 5) * 512 + ((d0f >> 3) & 3) * 128 + (d0f & 7)] = f2b(v0);
              Qimg[rowoff + (d1f >> 5) * 512 + ((d1f >> 3) & 3) * 128 + (d1f & 7)] = f2b(v1);
            }
        }
      }
    } else {
      const int c = hc;
      u16* Kimg = Kb + (size_t)(b * KVH + c) * 32 * 8192;
      u16* Vimg = VTb + (size_t)(b * KVH + c) * 32 * 8192;
#pragma unroll
      for (int j = 0; j < 4; ++j) {
        const int d = wn * 64 + j * 16 + r;         // 0..127
        const float bv = bkv[c * 128 + d];
#pragma unroll
        for (int i = 0; i < 4; ++i)
#pragma unroll
          for (int ii = 0; ii < 4; ++ii) {
            const int l = lbase + i * 16 + rg + ii; // key
            const u16 bf = f2b(acc[i][j][ii] + bv);
            const int lt = l & 63;
            Vimg[(size_t)(l >> 6) * 8192 + ((d >> 4) * 2 + ((lt >> 5) & 1)) * 512 +
                 ((lt >> 2) & 3) * 128 + (d & 15) * 8 + ((lt >> 4) & 1) * 4 + (lt & 3)] = bf;
            if (wn == 0)
              Kimg[(size_t)(l >> 6) * 8192 + ((lt >> 4) & 3) * 2048 + (d >> 5) * 512 +
                   ((d >> 3) & 3) * 128 + (lt & 15) * 8 + (d & 7)] = bf;
          }
      }
    }
  } else {
    // ---------- rk path: k_rope GEMM + rope -> K-image d>=64 ----------
    f32x4* red = (f32x4*)SB;                        // [4][2][64] = 8KB
    const int rid = id - 640;                       // 0..511
    const int bx = rid & 1;
    const int m0 = (rid >> 1) * 16;
    const int kq = hi * 8;
    const u16* ap  = xb + (size_t)(m0 + r) * DD + kq;
    const u16* wp0 = Wrkb + (size_t)(bx * 16 + r) * DD + kq;
    const u16* wp1 = Wrkb + (size_t)(bx * 16 + 32 + r) * DD + kq;
    f32x4 acc0 = {0.f, 0.f, 0.f, 0.f}, acc1 = {0.f, 0.f, 0.f, 0.f};
    for (int k = w * 512; k < w * 512 + 512; k += 32) {
      bf16x8 a  = *(const bf16x8*)(ap + k);
      bf16x8 b0 = *(const bf16x8*)(wp0 + k);
      bf16x8 b1 = *(const bf16x8*)(wp1 + k);
      acc0 = __builtin_amdgcn_mfma_f32_16x16x32_bf16(a, b0, acc0, 0, 0, 0);
      acc1 = __builtin_amdgcn_mfma_f32_16x16x32_bf16(a, b1, acc1, 0, 0, 0);
    }
    red[(w * 2 + 0) * 64 + lane] = acc0;
    red[(w * 2 + 1) * 64 + lane] = acc1;
    __syncthreads();
    if (w == 0) {
#pragma unroll
      for (int ww = 1; ww < 4; ++ww) {
        acc0 += red[(ww * 2 + 0) * 64 + lane];
        acc1 += red[(ww * 2 + 1) * 64 + lane];
      }
      const int dd0 = bx * 16 + r, dd1 = dd0 + 32;
      const float bv0 = brk[dd0], bv1 = brk[dd1];
      const int d0f = 64 + dd0, d1f = 64 + dd1;
#pragma unroll
      for (int i = 0; i < 4; ++i) {
        const int n = m0 + rg + i;                  // global row
        const int b = n >> 11, l = n & 2047;
        const size_t nb = (size_t)n * 64;
        const float c0 = cosb[nb + dd0], s0 = sinb[nb + dd0];
        const float c1 = cosb[nb + dd1], s1 = sinb[nb + dd1];
        const float a0 = acc0[i] + bv0;
        const float a1 = acc1[i] + bv1;
        const u16 v0 = f2b(a0 * c0 - a1 * s0);      // K col 64+dd0
        const u16 v1 = f2b(a1 * c1 + a0 * s1);      // K col 64+dd1
        const int lt = l & 63;
        const size_t loff = (size_t)(l >> 6) * 8192 + ((lt >> 4) & 3) * 2048 + (lt & 15) * 8;
#pragma unroll
        for (int c = 0; c < 4; ++c) {
          u16* Kimg = Kb + (size_t)(b * KVH + c) * 32 * 8192;
          Kimg[loff + (d0f >> 5) * 512 + ((d0f >> 3) & 3) * 128 + (d0f & 7)] = v0;
          Kimg[loff + (d1f >> 5) * 512 + ((d1f >> 3) & 3) * 128 + (d1f & 7)] = v1;
        }
      }
    }
  }
}

// ---------------- stage one 64-key tile for a 4-wave group ----------------
static __device__ __forceinline__ void stage_g(const u16* Kt, const u16* Vt,
                                               char* GB, int buf, int wg, int lane) {
#pragma unroll
  for (int i = 0; i < 4; ++i) {
    const int j = wg * 4 + i;                       // slot 0..15
    gload_lds16(Kt + (size_t)j * 512 + lane * 8, (u16*)(GB + buf * 16384) + j * 512);
    gload_lds16(Vt + (size_t)j * 512 + lane * 8, (u16*)(GB + 32768 + buf * 16384) + j * 512);
  }
}

// ---------------- MFMA flash attention v10: intra-block split-K, uniform blocks ----------------
__global__ __launch_bounds__(512, 2) void attn_mfma10(const u16* __restrict__ Qb,
                                                      const u16* __restrict__ Kb,
                                                      const u16* __restrict__ VTb,
                                                      u16* __restrict__ attn_bf) {
  const int id = blockIdx.x;
  const int g = id & 31;
  const int s = id >> 5;                            // 0..7
  const int bc = g & 7, hlow = g >> 3;              // id%8 == bc -> XCD clustering
  const int b = bc >> 2, c = bc & 3;
  const int h = c * 4 + hlow;
  const int bh = b * 16 + h;
  const int w = threadIdx.x >> 6, lane = threadIdx.x & 63;
  const int r = lane & 15, hi = lane >> 4, rg = hi * 4;
  const int grp = w >> 2, wg = w & 3;

  __shared__ __align__(16) char LB[131072];         // 2 groups x (K dbuf 32KB + V dbuf 32KB)
  char* GB = LB + grp * 65536;

  const u16* Ktg = Kb + (size_t)(b * KVH + c) * 32 * 8192;
  const u16* Vtg = VTb + (size_t)(b * KVH + c) * 32 * 8192;

  for (int ss = 0; ss < 2; ++ss) {
    const int qb = ss ? s : (15 - s);
    const int q0 = qb * 128 + wg * 32;              // this wave's 32 q rows
    const int half = qb + 1;                        // tiles per group (nt=2qb+2 even)
    const int tb = grp ? half : 0;                  // group's first tile

    bf16x8 qf[2][4];
#pragma unroll
    for (int qs = 0; qs < 2; ++qs) {
      const u16* qtb = Qb + (size_t)(bh * 128 + qb * 8 + wg * 2 + qs) * 2048;
#pragma unroll
      for (int ks = 0; ks < 4; ++ks)
        qf[qs][ks] = *(const bf16x8*)(qtb + ks * 512 + lane * 8);
    }

    float m_[2] = {-3.0e38f, -3.0e38f}, l_[2] = {0.f, 0.f};
    f32x4 o[2][8];
#pragma unroll
    for (int qs = 0; qs < 2; ++qs)
#pragma unroll
      for (int t = 0; t < 8; ++t) o[qs][t] = (f32x4){0.f, 0.f, 0.f, 0.f};

    stage_g(Ktg + (size_t)tb * 8192, Vtg + (size_t)tb * 8192, GB, 0, wg, lane);
    __syncthreads();
    int cur = 0;

    for (int t = 0; t < half; ++t) {
      if (t + 1 < half)
        stage_g(Ktg + (size_t)(tb + t + 1) * 8192, Vtg + (size_t)(tb + t + 1) * 8192,
                GB, cur ^ 1, wg, lane);
      const int s0 = (tb + t) * 64;

      if (s0 <= q0 + 31) {                          // wave-uniform skip (group B early q)
        const u16* Kl = (const u16*)(GB + cur * 16384);
        const u16* Vl = (const u16*)(GB + 32768 + cur * 16384);

        f32x4 st[2][4];
#pragma unroll
        for (int qs = 0; qs < 2; ++qs)
#pragma unroll
          for (int tt = 0; tt < 4; ++tt) st[qs][tt] = (f32x4){0.f, 0.f, 0.f, 0.f};
        __builtin_amdgcn_s_setprio(1);
#pragma unroll
        for (int tt = 0; tt < 4; ++tt) {
          bf16x8 kf[4];
#pragma unroll
          for (int ks = 0; ks < 4; ++ks)
            kf[ks] = *(const bf16x8*)(Kl + tt * 2048 + ks * 512 + lane * 8);
#pragma unroll
          for (int qs = 0; qs < 2; ++qs)
#pragma unroll
            for (int ks = 0; ks < 4; ++ks)
              st[qs][tt] = __builtin_amdgcn_mfma_f32_16x16x32_bf16(kf[ks], qf[qs][ks], st[qs][tt], 0, 0, 0);
        }
        __builtin_amdgcn_s_setprio(0);

        if (s0 + 63 > q0) {
#pragma unroll
          for (int qs = 0; qs < 2; ++qs)
#pragma unroll
            for (int tt = 0; tt < 4; ++tt)
#pragma unroll
              for (int i = 0; i < 4; ++i)
                if (s0 + tt * 16 + rg + i > q0 + qs * 16 + r) st[qs][tt][i] = -3.0e38f;
        }

        float vmax[2];
#pragma unroll
        for (int qs = 0; qs < 2; ++qs) {
          float v = st[qs][0][0];
#pragma unroll
          for (int tt = 0; tt < 4; ++tt)
#pragma unroll
            for (int i = 0; i < 4; ++i) v = fmaxf(v, st[qs][tt][i]);
          v = fmaxf(v, __shfl_xor(v, 16));
          v = fmaxf(v, __shfl_xor(v, 32));
          vmax[qs] = v;
        }
        const float grow = fmaxf(vmax[0] - m_[0], vmax[1] - m_[1]);
        if (!__all(grow <= 11.54f)) {
#pragma unroll
          for (int qs = 0; qs < 2; ++qs) {
            const float mn = fmaxf(m_[qs], vmax[qs]);
            const float cf = exp2f(m_[qs] - mn);
            l_[qs] *= cf;
            m_[qs] = mn;
#pragma unroll
            for (int tt = 0; tt < 8; ++tt)
#pragma unroll
              for (int i = 0; i < 4; ++i) o[qs][tt][i] *= cf;
          }
        }
        bf16x8 pa[2][2];
#pragma unroll
        for (int qs = 0; qs < 2; ++qs) {
          float ps = 0.f;
#pragma unroll
          for (int tt = 0; tt < 4; ++tt)
#pragma unroll
            for (int i = 0; i < 4; ++i) {
              st[qs][tt][i] = exp2f(st[qs][tt][i] - m_[qs]);
              ps += st[qs][tt][i];
            }
          ps += __shfl_xor(ps, 16);
          ps += __shfl_xor(ps, 32);
          l_[qs] += ps;
#pragma unroll
          for (int kb = 0; kb < 2; ++kb) {
            bf16x8 v;
#pragma unroll
            for (int jj = 0; jj < 8; ++jj)
              v[jj] = (short)f2b(st[qs][2 * kb + (jj >> 2)][jj & 3]);
            pa[qs][kb] = v;
          }
        }

        __builtin_amdgcn_s_setprio(1);
#pragma unroll
        for (int tt = 0; tt < 8; ++tt) {
#pragma unroll
          for (int kb = 0; kb < 2; ++kb) {
            bf16x8 vf = *(const bf16x8*)(Vl + tt * 1024 + kb * 512 + lane * 8);
#pragma unroll
            for (int qs = 0; qs < 2; ++qs)
              o[qs][tt] = __builtin_amdgcn_mfma_f32_16x16x32_bf16(pa[qs][kb], vf, o[qs][tt], 0, 0, 0);
          }
        }
        __builtin_amdgcn_s_setprio(0);
      }

      __syncthreads();
      cur ^= 1;
    }

    // ---- split-K combine ----
    float2* mlp = (float2*)(LB + 65536);
    if (hi == 0) {
      mlp[(w * 2 + 0) * 16 + r] = make_float2(m_[0], l_[0]);
      mlp[(w * 2 + 1) * 16 + r] = make_float2(m_[1], l_[1]);
    }
    __syncthreads();
    float lC[2], asc[2];
#pragma unroll
    for (int qs = 0; qs < 2; ++qs) {
      const float2 p = mlp[((w ^ 4) * 2 + qs) * 16 + r];
      const float mn = fmaxf(m_[qs], p.x);
      const float a1 = exp2f(m_[qs] - mn);
      lC[qs] = l_[qs] * a1 + p.y * exp2f(p.x - mn);
      asc[qs] = a1;
    }
#pragma unroll
    for (int qs = 0; qs < 2; ++qs) {
      float ai[4];
#pragma unroll
      for (int i = 0; i < 4; ++i) ai[i] = __shfl(asc[qs], (lane & 48) + rg + i);
#pragma unroll
      for (int tt = 0; tt < 8; ++tt)
#pragma unroll
        for (int i = 0; i < 4; ++i) o[qs][tt][i] *= ai[i];
    }
    if (grp == 1) {
#pragma unroll
      for (int qs = 0; qs < 2; ++qs)
#pragma unroll
        for (int tt = 0; tt < 8; ++tt)
          *(f32x4*)(LB + wg * 16384 + (qs * 8 + tt) * 1024 + lane * 16) = o[qs][tt];
    }
    __syncthreads();
    if (grp == 0) {
#pragma unroll
      for (int qs = 0; qs < 2; ++qs) {
#pragma unroll
        for (int tt = 0; tt < 8; ++tt)
          o[qs][tt] += *(const f32x4*)(LB + wg * 16384 + (qs * 8 + tt) * 1024 + lane * 16);
        const float il = 1.f / lC[qs];
        float inv[4];
#pragma unroll
        for (int i = 0; i < 4; ++i) inv[i] = __shfl(il, (lane & 48) + rg + i);
        u16* op = attn_bf + (size_t)(b * LL + q0 + qs * 16 + rg) * DD + h * HDD;
#pragma unroll
        for (int tt = 0; tt < 8; ++tt)
#pragma unroll
          for (int i = 0; i < 4; ++i)
            op[(size_t)i * DD + tt * 16 + r] = f2b(o[qs][tt][i] * inv[i]);
      }
    }
    __syncthreads();
  }
}

extern "C" void kernel_launch(void* const* d_in, const int* in_sizes, int n_in,
                              void* d_out, int out_size, void* d_ws, size_t ws_size,
                              hipStream_t stream) {
  const float* x    = (const float*)d_in[0];
  const float* cosb = (const float*)d_in[1];
  const float* sinb = (const float*)d_in[2];
  const float* Wq   = (const float*)d_in[3];
  const float* bq   = (const float*)d_in[4];
  const float* Wkv  = (const float*)d_in[5];
  const float* bkv  = (const float*)d_in[6];
  const float* Wrk  = (const float*)d_in[7];
  const float* brk  = (const float*)d_in[8];
  const float* Wo   = (const float*)d_in[9];
  const float* bo   = (const float*)d_in[10];
  float* out = (float*)d_out;

  // Workspace layout (78,905,344 B total):
  char* ws = (char*)d_ws;
  u16*   Qb    = (u16*)(ws);                        // 16,777,216
  u16*   attn_bf = (u16*)(ws + 16777216);           // 16,777,216
  u16*   xb    = (u16*)(ws + 33554432);             // 16,777,216
  u16*   Wqb   = (u16*)(ws + 50331648);             //  8,388,608
  u16*   Wob   = (u16*)(ws + 58720256);             //  8,388,608
  u16*   Wkvb  = (u16*)(ws + 67108864);             //  2,097,152
  u16*   Wrkb  = (u16*)(ws + 69206016);             //    262,144
  u16*   Kb    = (u16*)(ws + 70516736);             //  4,194,304
  u16*   VTb   = (u16*)(ws + 74711040);             //  4,194,304 -> 78,905,344

  // 1) all casts in one kernel (4,489,216 float4 / 256 = 17,536 blocks)
  cast_all<<<17536, 256, 0, stream>>>(x, Wq, Wkv, Wrk, Wo, xb, Wqb, Wkvb, Wrkb, Wob);

  // 2) unified projection kernel -> all attention operand images (one launch)
  proj_fused<<<1152, 256, 0, stream>>>(xb, Wqb, bq, Wkvb, bkv, Wrkb, brk,
                                       cosb, sinb, Qb, Kb, VTb);

  // 3) MFMA flash attention v10 -> bf16
  attn_mfma10<<<dim3(256), 512, 0, stream>>>(Qb, Kb, VTb, attn_bf);

  // 4) output projection -> d_out (f32)
  gemm128<<<dim3(DD / 128, MM / 128), 256, 0, stream>>>(attn_bf, Wob, bo, out, MM, DD, DD);
}

// Round 24
// 231.402 us; speedup vs baseline: 1.0608x; 1.0608x over previous
//
#include <hip/hip_runtime.h>
#include <hip/hip_bf16.h>

// Problem constants
#define BB   2
#define LL   2048
#define DD   2048
#define HH   16
#define KVH  4
#define HDD  128
#define RDD  64
#define MM   (BB*LL)   // 4096 rows of x

typedef __attribute__((ext_vector_type(4))) float f32x4;
typedef __attribute__((ext_vector_type(8))) short bf16x8;
typedef unsigned short u16;

static __device__ __forceinline__ u16 f2b(float f) {
  __hip_bfloat16 b = __float2bfloat16(f);
  return *(const u16*)&b;
}

// async global(16B/lane) -> LDS (wave-uniform base + lane*16)
static __device__ __forceinline__ void gload_lds16(const void* g, void* l) {
  __builtin_amdgcn_global_load_lds(
      (const __attribute__((address_space(1))) unsigned int*)g,
      (__attribute__((address_space(3))) unsigned int*)l, 16, 0, 0);
}

// log2(e)/sqrt(128): scores land in exp2 domain
#define QSCALE 0.1275174313f

// ---------------- all f32->bf16 casts in ONE kernel (5 segments) ----------------
// float4 counts: x 2,097,152 | Wq 1,048,576 | Wkv 262,144 | Wrk 32,768 | Wo 1,048,576
__global__ __launch_bounds__(256) void cast_all(const float* __restrict__ x,
                                                const float* __restrict__ Wq,
                                                const float* __restrict__ Wkv,
                                                const float* __restrict__ Wrk,
                                                const float* __restrict__ Wo,
                                                u16* __restrict__ xb, u16* __restrict__ Wqb,
                                                u16* __restrict__ Wkvb, u16* __restrict__ Wrkb,
                                                u16* __restrict__ Wob) {
  const int i = blockIdx.x * 256 + threadIdx.x;    // float4 index, total 4,489,216
  const float* src; u16* dst; int off;
  if (i < 2097152)      { src = x;   dst = xb;   off = i; }
  else if (i < 3145728) { src = Wq;  dst = Wqb;  off = i - 2097152; }
  else if (i < 3407872) { src = Wkv; dst = Wkvb; off = i - 3145728; }
  else if (i < 3440640) { src = Wrk; dst = Wrkb; off = i - 3407872; }
  else                  { src = Wo;  dst = Wob;  off = i - 3440640; }
  float4 v = ((const float4*)src)[off];
  ushort4 o;
  o.x = f2b(v.x); o.y = f2b(v.y); o.z = f2b(v.z); o.w = f2b(v.w);
  ((ushort4*)dst)[off] = o;
}

// ---------------- m97-style 128x128 tile GEMM (f32 out, for Wo) ----------------
__global__ __launch_bounds__(256) void gemm128(const u16* __restrict__ A,
                                               const u16* __restrict__ W,
                                               const float* __restrict__ bias,
                                               float* __restrict__ C,
                                               int M, int N, int K) {
  __shared__ u16 As[128 * 32];
  __shared__ u16 Bs[128 * 32];
  const int w = threadIdx.x >> 6, lane = threadIdx.x & 63;
  const int r = lane & 15, hi = lane >> 4, rg = hi * 4;
  const int wm = w >> 1, wn = w & 1;
  const int m0 = blockIdx.y * 128, n0 = blockIdx.x * 128;
  const int srow = w * 32 + (lane >> 2);
  const int scb  = (lane & 3) * 16;
  f32x4 acc[4][4];
#pragma unroll
  for (int i = 0; i < 4; ++i)
#pragma unroll
    for (int j = 0; j < 4; ++j) acc[i][j] = (f32x4){0.f, 0.f, 0.f, 0.f};

  for (int k0 = 0; k0 < K; k0 += 32) {
#pragma unroll
    for (int i = 0; i < 2; ++i) {
      gload_lds16((const char*)(A + (size_t)(m0 + srow + i * 16) * K + k0) + scb,
                  (char*)As + (w * 2 + i) * 1024);
      gload_lds16((const char*)(W + (size_t)(n0 + srow + i * 16) * K + k0) + scb,
                  (char*)Bs + (w * 2 + i) * 1024);
    }
    __syncthreads();
    bf16x8 a[4], b[4];
#pragma unroll
    for (int i = 0; i < 4; ++i)
      a[i] = *(const bf16x8*)((const char*)As + (wm * 64 + i * 16 + r) * 64 + hi * 16);
#pragma unroll
    for (int j = 0; j < 4; ++j)
      b[j] = *(const bf16x8*)((const char*)Bs + (wn * 64 + j * 16 + r) * 64 + hi * 16);
#pragma unroll
    for (int i = 0; i < 4; ++i)
#pragma unroll
      for (int j = 0; j < 4; ++j)
        acc[i][j] = __builtin_amdgcn_mfma_f32_16x16x32_bf16(a[i], b[j], acc[i][j], 0, 0, 0);
    __syncthreads();
  }
#pragma unroll
  for (int j = 0; j < 4; ++j) {
    const float bv = bias[n0 + wn * 64 + j * 16 + r];
#pragma unroll
    for (int i = 0; i < 4; ++i)
#pragma unroll
      for (int ii = 0; ii < 4; ++ii)
        C[(size_t)(m0 + wm * 64 + i * 16 + rg + ii) * N + n0 + wn * 64 + j * 16 + r] =
            acc[i][j][ii] + bv;
  }
}

// ---------------- fused Q GEMM: q = x@Wq^T + bq, rope+scale, bf16 granule images ----
__global__ __launch_bounds__(256) void gemm_q_fused(const u16* __restrict__ A,
                                                    const u16* __restrict__ W,
                                                    const float* __restrict__ bias,
                                                    const float* __restrict__ cosb,
                                                    const float* __restrict__ sinb,
                                                    u16* __restrict__ Qb) {
  __shared__ u16 As[128 * 32];
  __shared__ u16 Bs[128 * 32];
  const int w = threadIdx.x >> 6, lane = threadIdx.x & 63;
  const int r = lane & 15, hi = lane >> 4, rg = hi * 4;
  const int wm = w >> 1, wn = w & 1;
  const int h = blockIdx.x;
  const int m0 = blockIdx.y * 128, n0 = h * 128;
  const int srow = w * 32 + (lane >> 2);
  const int scb  = (lane & 3) * 16;
  f32x4 acc[4][4];
#pragma unroll
  for (int i = 0; i < 4; ++i)
#pragma unroll
    for (int j = 0; j < 4; ++j) acc[i][j] = (f32x4){0.f, 0.f, 0.f, 0.f};

  for (int k0 = 0; k0 < DD; k0 += 32) {
#pragma unroll
    for (int i = 0; i < 2; ++i) {
      gload_lds16((const char*)(A + (size_t)(m0 + srow + i * 16) * DD + k0) + scb,
                  (char*)As + (w * 2 + i) * 1024);
      gload_lds16((const char*)(W + (size_t)(n0 + srow + i * 16) * DD + k0) + scb,
                  (char*)Bs + (w * 2 + i) * 1024);
    }
    __syncthreads();
    bf16x8 a[4], b[4];
#pragma unroll
    for (int i = 0; i < 4; ++i)
      a[i] = *(const bf16x8*)((const char*)As + (wm * 64 + i * 16 + r) * 64 + hi * 16);
#pragma unroll
    for (int j = 0; j < 4; ++j)
      b[j] = *(const bf16x8*)((const char*)Bs + (wn * 64 + j * 16 + r) * 64 + hi * 16);
#pragma unroll
    for (int i = 0; i < 4; ++i)
#pragma unroll
      for (int j = 0; j < 4; ++j)
        acc[i][j] = __builtin_amdgcn_mfma_f32_16x16x32_bf16(a[i], b[j], acc[i][j], 0, 0, 0);
    __syncthreads();
  }

  const int b = m0 >> 11;
  const int lbase = (m0 & 2047) + wm * 64;
  u16* Qimg = Qb + (size_t)((b * 16 + h) * 128) * 2048;
  if (wn == 0) {
#pragma unroll
    for (int j = 0; j < 4; ++j) {
      const int d = j * 16 + r;                     // < 64: no rope
      const float bv = bias[h * 128 + d];
#pragma unroll
      for (int i = 0; i < 4; ++i)
#pragma unroll
        for (int ii = 0; ii < 4; ++ii) {
          const int l = lbase + i * 16 + rg + ii;
          Qimg[(size_t)(l >> 4) * 2048 + (d >> 5) * 512 + ((d >> 3) & 3) * 128 +
               (l & 15) * 8 + (d & 7)] = f2b((acc[i][j][ii] + bv) * QSCALE);
        }
    }
  } else {
#pragma unroll
    for (int jp = 0; jp < 2; ++jp) {
      const int dd0 = jp * 16 + r;                  // 0..31
      const int dd1 = dd0 + 32;                     // 32..63
      const float bv0 = bias[h * 128 + 64 + dd0];
      const float bv1 = bias[h * 128 + 64 + dd1];
#pragma unroll
      for (int i = 0; i < 4; ++i)
#pragma unroll
        for (int ii = 0; ii < 4; ++ii) {
          const int l = lbase + i * 16 + rg + ii;
          const size_t nb = (size_t)(b * 2048 + l) * 64;
          const float c0 = cosb[nb + dd0], s0 = sinb[nb + dd0];
          const float c1 = cosb[nb + dd1], s1 = sinb[nb + dd1];
          const float a0 = acc[i][jp][ii] + bv0;
          const float a1 = acc[i][jp + 2][ii] + bv1;
          const float v0 = (a0 * c0 - a1 * s0) * QSCALE;
          const float v1 = (a1 * c1 + a0 * s1) * QSCALE;
          const int d0f = 64 + dd0, d1f = 64 + dd1;
          const size_t rowoff = (size_t)(l >> 4) * 2048 + (l & 15) * 8;
          Qimg[rowoff + (d0f >> 5) * 512 + ((d0f >> 3) & 3) * 128 + (d0f & 7)] = f2b(v0);
          Qimg[rowoff + (d1f >> 5) * 512 + ((d1f >> 3) & 3) * 128 + (d1f & 7)] = f2b(v1);
        }
    }
  }
}

// ---------------- fused KV GEMM -> 64-key-tile K-tied + interleaved-V images ----------------
__global__ __launch_bounds__(256) void gemm_kv_fused(const u16* __restrict__ A,
                                                     const u16* __restrict__ W,
                                                     const float* __restrict__ bias,
                                                     u16* __restrict__ Kb,
                                                     u16* __restrict__ VTb) {
  __shared__ u16 As[128 * 32];
  __shared__ u16 Bs[128 * 32];
  const int w = threadIdx.x >> 6, lane = threadIdx.x & 63;
  const int r = lane & 15, hi = lane >> 4, rg = hi * 4;
  const int wm = w >> 1, wn = w & 1;
  const int c = blockIdx.x;
  const int m0 = blockIdx.y * 128, n0 = c * 128;
  const int srow = w * 32 + (lane >> 2);
  const int scb  = (lane & 3) * 16;
  f32x4 acc[4][4];
#pragma unroll
  for (int i = 0; i < 4; ++i)
#pragma unroll
    for (int j = 0; j < 4; ++j) acc[i][j] = (f32x4){0.f, 0.f, 0.f, 0.f};

  for (int k0 = 0; k0 < DD; k0 += 32) {
#pragma unroll
    for (int i = 0; i < 2; ++i) {
      gload_lds16((const char*)(A + (size_t)(m0 + srow + i * 16) * DD + k0) + scb,
                  (char*)As + (w * 2 + i) * 1024);
      gload_lds16((const char*)(W + (size_t)(n0 + srow + i * 16) * DD + k0) + scb,
                  (char*)Bs + (w * 2 + i) * 1024);
    }
    __syncthreads();
    bf16x8 a[4], b[4];
#pragma unroll
    for (int i = 0; i < 4; ++i)
      a[i] = *(const bf16x8*)((const char*)As + (wm * 64 + i * 16 + r) * 64 + hi * 16);
#pragma unroll
    for (int j = 0; j < 4; ++j)
      b[j] = *(const bf16x8*)((const char*)Bs + (wn * 64 + j * 16 + r) * 64 + hi * 16);
#pragma unroll
    for (int i = 0; i < 4; ++i)
#pragma unroll
      for (int j = 0; j < 4; ++j)
        acc[i][j] = __builtin_amdgcn_mfma_f32_16x16x32_bf16(a[i], b[j], acc[i][j], 0, 0, 0);
    __syncthreads();
  }

  const int b = m0 >> 11;
  const int lbase = (m0 & 2047) + wm * 64;
  u16* Kimg = Kb + (size_t)(b * KVH + c) * 32 * 8192;
  u16* Vimg = VTb + (size_t)(b * KVH + c) * 32 * 8192;
#pragma unroll
  for (int j = 0; j < 4; ++j) {
    const int d = wn * 64 + j * 16 + r;             // 0..127
    const float bv = bias[c * 128 + d];
#pragma unroll
    for (int i = 0; i < 4; ++i)
#pragma unroll
      for (int ii = 0; ii < 4; ++ii) {
        const int l = lbase + i * 16 + rg + ii;     // key
        const u16 bf = f2b(acc[i][j][ii] + bv);
        const int lt = l & 63;
        Vimg[(size_t)(l >> 6) * 8192 + ((d >> 4) * 2 + ((lt >> 5) & 1)) * 512 +
             ((lt >> 2) & 3) * 128 + (d & 15) * 8 + ((lt >> 4) & 1) * 4 + (lt & 3)] = bf;
        if (wn == 0)
          Kimg[(size_t)(l >> 6) * 8192 + ((lt >> 4) & 3) * 2048 + (d >> 5) * 512 +
               ((d >> 3) & 3) * 128 + (lt & 15) * 8 + (d & 7)] = bf;
      }
  }
}

// ---------------- fused RK GEMM: k_rope = x@Wrk^T + brk, rope, -> K-image d>=64 ----
__global__ __launch_bounds__(256) void gemm_rk_fused(const u16* __restrict__ A,
                                                     const u16* __restrict__ Wrkb,
                                                     const float* __restrict__ brk,
                                                     const float* __restrict__ cosb,
                                                     const float* __restrict__ sinb,
                                                     u16* __restrict__ Kb) {
  __shared__ f32x4 red[4][2][64];
  const int w = threadIdx.x >> 6, lane = threadIdx.x & 63;
  const int bx = blockIdx.x;                        // 0..1
  const int m0 = blockIdx.y * 16;
  const int r = lane & 15;
  const int kq = (lane >> 4) * 8;
  const u16* ap  = A + (size_t)(m0 + r) * DD + kq;
  const u16* wp0 = Wrkb + (size_t)(bx * 16 + r) * DD + kq;
  const u16* wp1 = Wrkb + (size_t)(bx * 16 + 32 + r) * DD + kq;
  f32x4 acc0 = {0.f, 0.f, 0.f, 0.f}, acc1 = {0.f, 0.f, 0.f, 0.f};
  for (int k = w * 512; k < w * 512 + 512; k += 32) {
    bf16x8 a  = *(const bf16x8*)(ap + k);
    bf16x8 b0 = *(const bf16x8*)(wp0 + k);
    bf16x8 b1 = *(const bf16x8*)(wp1 + k);
    acc0 = __builtin_amdgcn_mfma_f32_16x16x32_bf16(a, b0, acc0, 0, 0, 0);
    acc1 = __builtin_amdgcn_mfma_f32_16x16x32_bf16(a, b1, acc1, 0, 0, 0);
  }
  red[w][0][lane] = acc0;
  red[w][1][lane] = acc1;
  __syncthreads();
  if (w == 0) {
#pragma unroll
    for (int ww = 1; ww < 4; ++ww) {
      acc0 += red[ww][0][lane];
      acc1 += red[ww][1][lane];
    }
    const int rg = (lane >> 4) * 4;
    const int dd0 = bx * 16 + r, dd1 = dd0 + 32;
    const float bv0 = brk[dd0], bv1 = brk[dd1];
    const int d0f = 64 + dd0, d1f = 64 + dd1;
#pragma unroll
    for (int i = 0; i < 4; ++i) {
      const int n = m0 + rg + i;                    // global row
      const int b = n >> 11, l = n & 2047;
      const size_t nb = (size_t)n * 64;
      const float c0 = cosb[nb + dd0], s0 = sinb[nb + dd0];
      const float c1 = cosb[nb + dd1], s1 = sinb[nb + dd1];
      const float a0 = acc0[i] + bv0;
      const float a1 = acc1[i] + bv1;
      const u16 v0 = f2b(a0 * c0 - a1 * s0);        // K col 64+dd0
      const u16 v1 = f2b(a1 * c1 + a0 * s1);        // K col 64+dd1
      const int lt = l & 63;
      const size_t loff = (size_t)(l >> 6) * 8192 + ((lt >> 4) & 3) * 2048 + (lt & 15) * 8;
#pragma unroll
      for (int c = 0; c < 4; ++c) {
        u16* Kimg = Kb + (size_t)(b * KVH + c) * 32 * 8192;
        Kimg[loff + (d0f >> 5) * 512 + ((d0f >> 3) & 3) * 128 + (d0f & 7)] = v0;
        Kimg[loff + (d1f >> 5) * 512 + ((d1f >> 3) & 3) * 128 + (d1f & 7)] = v1;
      }
    }
  }
}

// ---------------- stage one 64-key tile for a 4-wave group ----------------
static __device__ __forceinline__ void stage_g(const u16* Kt, const u16* Vt,
                                               char* GB, int buf, int wg, int lane) {
#pragma unroll
  for (int i = 0; i < 4; ++i) {
    const int j = wg * 4 + i;                       // slot 0..15
    gload_lds16(Kt + (size_t)j * 512 + lane * 8, (u16*)(GB + buf * 16384) + j * 512);
    gload_lds16(Vt + (size_t)j * 512 + lane * 8, (u16*)(GB + 32768 + buf * 16384) + j * 512);
  }
}

// ---------------- MFMA flash attention v10: intra-block split-K, uniform blocks ----------------
__global__ __launch_bounds__(512, 2) void attn_mfma10(const u16* __restrict__ Qb,
                                                      const u16* __restrict__ Kb,
                                                      const u16* __restrict__ VTb,
                                                      u16* __restrict__ attn_bf) {
  const int id = blockIdx.x;
  const int g = id & 31;
  const int s = id >> 5;                            // 0..7
  const int bc = g & 7, hlow = g >> 3;              // id%8 == bc -> XCD clustering
  const int b = bc >> 2, c = bc & 3;
  const int h = c * 4 + hlow;
  const int bh = b * 16 + h;
  const int w = threadIdx.x >> 6, lane = threadIdx.x & 63;
  const int r = lane & 15, hi = lane >> 4, rg = hi * 4;
  const int grp = w >> 2, wg = w & 3;

  __shared__ __align__(16) char LB[131072];         // 2 groups x (K dbuf 32KB + V dbuf 32KB)
  char* GB = LB + grp * 65536;

  const u16* Ktg = Kb + (size_t)(b * KVH + c) * 32 * 8192;
  const u16* Vtg = VTb + (size_t)(b * KVH + c) * 32 * 8192;

  for (int ss = 0; ss < 2; ++ss) {
    const int qb = ss ? s : (15 - s);
    const int q0 = qb * 128 + wg * 32;              // this wave's 32 q rows
    const int half = qb + 1;                        // tiles per group (nt=2qb+2 even)
    const int tb = grp ? half : 0;                  // group's first tile

    bf16x8 qf[2][4];
#pragma unroll
    for (int qs = 0; qs < 2; ++qs) {
      const u16* qtb = Qb + (size_t)(bh * 128 + qb * 8 + wg * 2 + qs) * 2048;
#pragma unroll
      for (int ks = 0; ks < 4; ++ks)
        qf[qs][ks] = *(const bf16x8*)(qtb + ks * 512 + lane * 8);
    }

    float m_[2] = {-3.0e38f, -3.0e38f}, l_[2] = {0.f, 0.f};
    f32x4 o[2][8];
#pragma unroll
    for (int qs = 0; qs < 2; ++qs)
#pragma unroll
      for (int t = 0; t < 8; ++t) o[qs][t] = (f32x4){0.f, 0.f, 0.f, 0.f};

    stage_g(Ktg + (size_t)tb * 8192, Vtg + (size_t)tb * 8192, GB, 0, wg, lane);
    __syncthreads();
    int cur = 0;

    for (int t = 0; t < half; ++t) {
      if (t + 1 < half)
        stage_g(Ktg + (size_t)(tb + t + 1) * 8192, Vtg + (size_t)(tb + t + 1) * 8192,
                GB, cur ^ 1, wg, lane);
      const int s0 = (tb + t) * 64;

      if (s0 <= q0 + 31) {                          // wave-uniform skip (group B early q)
        const u16* Kl = (const u16*)(GB + cur * 16384);
        const u16* Vl = (const u16*)(GB + 32768 + cur * 16384);

        f32x4 st[2][4];
#pragma unroll
        for (int qs = 0; qs < 2; ++qs)
#pragma unroll
          for (int tt = 0; tt < 4; ++tt) st[qs][tt] = (f32x4){0.f, 0.f, 0.f, 0.f};
        __builtin_amdgcn_s_setprio(1);
#pragma unroll
        for (int tt = 0; tt < 4; ++tt) {
          bf16x8 kf[4];
#pragma unroll
          for (int ks = 0; ks < 4; ++ks)
            kf[ks] = *(const bf16x8*)(Kl + tt * 2048 + ks * 512 + lane * 8);
#pragma unroll
          for (int qs = 0; qs < 2; ++qs)
#pragma unroll
            for (int ks = 0; ks < 4; ++ks)
              st[qs][tt] = __builtin_amdgcn_mfma_f32_16x16x32_bf16(kf[ks], qf[qs][ks], st[qs][tt], 0, 0, 0);
        }
        __builtin_amdgcn_s_setprio(0);

        if (s0 + 63 > q0) {
#pragma unroll
          for (int qs = 0; qs < 2; ++qs)
#pragma unroll
            for (int tt = 0; tt < 4; ++tt)
#pragma unroll
              for (int i = 0; i < 4; ++i)
                if (s0 + tt * 16 + rg + i > q0 + qs * 16 + r) st[qs][tt][i] = -3.0e38f;
        }

        float vmax[2];
#pragma unroll
        for (int qs = 0; qs < 2; ++qs) {
          float v = st[qs][0][0];
#pragma unroll
          for (int tt = 0; tt < 4; ++tt)
#pragma unroll
            for (int i = 0; i < 4; ++i) v = fmaxf(v, st[qs][tt][i]);
          v = fmaxf(v, __shfl_xor(v, 16));
          v = fmaxf(v, __shfl_xor(v, 32));
          vmax[qs] = v;
        }
        const float grow = fmaxf(vmax[0] - m_[0], vmax[1] - m_[1]);
        if (!__all(grow <= 11.54f)) {
#pragma unroll
          for (int qs = 0; qs < 2; ++qs) {
            const float mn = fmaxf(m_[qs], vmax[qs]);
            const float cf = exp2f(m_[qs] - mn);
            l_[qs] *= cf;
            m_[qs] = mn;
#pragma unroll
            for (int tt = 0; tt < 8; ++tt)
#pragma unroll
              for (int i = 0; i < 4; ++i) o[qs][tt][i] *= cf;
          }
        }
        bf16x8 pa[2][2];
#pragma unroll
        for (int qs = 0; qs < 2; ++qs) {
          float ps = 0.f;
#pragma unroll
          for (int tt = 0; tt < 4; ++tt)
#pragma unroll
            for (int i = 0; i < 4; ++i) {
              st[qs][tt][i] = exp2f(st[qs][tt][i] - m_[qs]);
              ps += st[qs][tt][i];
            }
          ps += __shfl_xor(ps, 16);
          ps += __shfl_xor(ps, 32);
          l_[qs] += ps;
#pragma unroll
          for (int kb = 0; kb < 2; ++kb) {
            bf16x8 v;
#pragma unroll
            for (int jj = 0; jj < 8; ++jj)
              v[jj] = (short)f2b(st[qs][2 * kb + (jj >> 2)][jj & 3]);
            pa[qs][kb] = v;
          }
        }

        __builtin_amdgcn_s_setprio(1);
#pragma unroll
        for (int tt = 0; tt < 8; ++tt) {
#pragma unroll
          for (int kb = 0; kb < 2; ++kb) {
            bf16x8 vf = *(const bf16x8*)(Vl + tt * 1024 + kb * 512 + lane * 8);
#pragma unroll
            for (int qs = 0; qs < 2; ++qs)
              o[qs][tt] = __builtin_amdgcn_mfma_f32_16x16x32_bf16(pa[qs][kb], vf, o[qs][tt], 0, 0, 0);
          }
        }
        __builtin_amdgcn_s_setprio(0);
      }

      __syncthreads();
      cur ^= 1;
    }

    // ---- split-K combine ----
    float2* mlp = (float2*)(LB + 65536);
    if (hi == 0) {
      mlp[(w * 2 + 0) * 16 + r] = make_float2(m_[0], l_[0]);
      mlp[(w * 2 + 1) * 16 + r] = make_float2(m_[1], l_[1]);
    }
    __syncthreads();
    float lC[2], asc[2];
#pragma unroll
    for (int qs = 0; qs < 2; ++qs) {
      const float2 p = mlp[((w ^ 4) * 2 + qs) * 16 + r];
      const float mn = fmaxf(m_[qs], p.x);
      const float a1 = exp2f(m_[qs] - mn);
      lC[qs] = l_[qs] * a1 + p.y * exp2f(p.x - mn);
      asc[qs] = a1;
    }
#pragma unroll
    for (int qs = 0; qs < 2; ++qs) {
      float ai[4];
#pragma unroll
      for (int i = 0; i < 4; ++i) ai[i] = __shfl(asc[qs], (lane & 48) + rg + i);
#pragma unroll
      for (int tt = 0; tt < 8; ++tt)
#pragma unroll
        for (int i = 0; i < 4; ++i) o[qs][tt][i] *= ai[i];
    }
    if (grp == 1) {
#pragma unroll
      for (int qs = 0; qs < 2; ++qs)
#pragma unroll
        for (int tt = 0; tt < 8; ++tt)
          *(f32x4*)(LB + wg * 16384 + (qs * 8 + tt) * 1024 + lane * 16) = o[qs][tt];
    }
    __syncthreads();
    if (grp == 0) {
#pragma unroll
      for (int qs = 0; qs < 2; ++qs) {
#pragma unroll
        for (int tt = 0; tt < 8; ++tt)
          o[qs][tt] += *(const f32x4*)(LB + wg * 16384 + (qs * 8 + tt) * 1024 + lane * 16);
        const float il = 1.f / lC[qs];
        float inv[4];
#pragma unroll
        for (int i = 0; i < 4; ++i) inv[i] = __shfl(il, (lane & 48) + rg + i);
        u16* op = attn_bf + (size_t)(b * LL + q0 + qs * 16 + rg) * DD + h * HDD;
#pragma unroll
        for (int tt = 0; tt < 8; ++tt)
#pragma unroll
          for (int i = 0; i < 4; ++i)
            op[(size_t)i * DD + tt * 16 + r] = f2b(o[qs][tt][i] * inv[i]);
      }
    }
    __syncthreads();
  }
}

extern "C" void kernel_launch(void* const* d_in, const int* in_sizes, int n_in,
                              void* d_out, int out_size, void* d_ws, size_t ws_size,
                              hipStream_t stream) {
  const float* x    = (const float*)d_in[0];
  const float* cosb = (const float*)d_in[1];
  const float* sinb = (const float*)d_in[2];
  const float* Wq   = (const float*)d_in[3];
  const float* bq   = (const float*)d_in[4];
  const float* Wkv  = (const float*)d_in[5];
  const float* bkv  = (const float*)d_in[6];
  const float* Wrk  = (const float*)d_in[7];
  const float* brk  = (const float*)d_in[8];
  const float* Wo   = (const float*)d_in[9];
  const float* bo   = (const float*)d_in[10];
  float* out = (float*)d_out;

  // Workspace layout (78,905,344 B total):
  char* ws = (char*)d_ws;
  u16*   Qb    = (u16*)(ws);                        // 16,777,216
  u16*   attn_bf = (u16*)(ws + 16777216);           // 16,777,216
  u16*   xb    = (u16*)(ws + 33554432);             // 16,777,216
  u16*   Wqb   = (u16*)(ws + 50331648);             //  8,388,608
  u16*   Wob   = (u16*)(ws + 58720256);             //  8,388,608
  u16*   Wkvb  = (u16*)(ws + 67108864);             //  2,097,152
  u16*   Wrkb  = (u16*)(ws + 69206016);             //    262,144
  u16*   Kb    = (u16*)(ws + 70516736);             //  4,194,304
  u16*   VTb   = (u16*)(ws + 74711040);             //  4,194,304 -> 78,905,344

  // 1) all casts in one kernel (4,489,216 float4 / 256 = 17,536 blocks)
  cast_all<<<17536, 256, 0, stream>>>(x, Wq, Wkv, Wrk, Wo, xb, Wqb, Wkvb, Wrkb, Wob);

  // 2) fused projections -> attention operand images (no f32 intermediates)
  gemm_q_fused<<<dim3(HH, MM / 128), 256, 0, stream>>>(xb, Wqb, bq, cosb, sinb, Qb);
  gemm_kv_fused<<<dim3(KVH, MM / 128), 256, 0, stream>>>(xb, Wkvb, bkv, Kb, VTb);
  gemm_rk_fused<<<dim3(2, MM / 16), 256, 0, stream>>>(xb, Wrkb, brk, cosb, sinb, Kb);

  // 3) MFMA flash attention v10 -> bf16
  attn_mfma10<<<dim3(256), 512, 0, stream>>>(Qb, Kb, VTb, attn_bf);

  // 4) output projection -> d_out (f32)
  gemm128<<<dim3(DD / 128, MM / 128), 256, 0, stream>>>(attn_bf, Wob, bo, out, MM, DD, DD);
}

// Round 25
// 216.567 us; speedup vs baseline: 1.1335x; 1.0685x over previous
//
#include <hip/hip_runtime.h>
#include <hip/hip_bf16.h>

// Problem constants
#define BB   2
#define LL   2048
#define DD   2048
#define HH   16
#define KVH  4
#define HDD  128
#define RDD  64
#define MM   (BB*LL)   // 4096 rows of x

typedef __attribute__((ext_vector_type(4))) float f32x4;
typedef __attribute__((ext_vector_type(8))) short bf16x8;
typedef unsigned short u16;

static __device__ __forceinline__ u16 f2b(float f) {
  __hip_bfloat16 b = __float2bfloat16(f);
  return *(const u16*)&b;
}

// async global(16B/lane) -> LDS (wave-uniform base + lane*16)
static __device__ __forceinline__ void gload_lds16(const void* g, void* l) {
  __builtin_amdgcn_global_load_lds(
      (const __attribute__((address_space(1))) unsigned int*)g,
      (__attribute__((address_space(3))) unsigned int*)l, 16, 0, 0);
}

// log2(e)/sqrt(128): scores land in exp2 domain
#define QSCALE 0.1275174313f

// ---------------- all f32->bf16 casts in ONE kernel (5 segments) ----------------
// float4 counts: x 2,097,152 | Wq 1,048,576 | Wkv 262,144 | Wrk 32,768 | Wo 1,048,576
__global__ __launch_bounds__(256) void cast_all(const float* __restrict__ x,
                                                const float* __restrict__ Wq,
                                                const float* __restrict__ Wkv,
                                                const float* __restrict__ Wrk,
                                                const float* __restrict__ Wo,
                                                u16* __restrict__ xb, u16* __restrict__ Wqb,
                                                u16* __restrict__ Wkvb, u16* __restrict__ Wrkb,
                                                u16* __restrict__ Wob) {
  const int i = blockIdx.x * 256 + threadIdx.x;    // float4 index, total 4,489,216
  const float* src; u16* dst; int off;
  if (i < 2097152)      { src = x;   dst = xb;   off = i; }
  else if (i < 3145728) { src = Wq;  dst = Wqb;  off = i - 2097152; }
  else if (i < 3407872) { src = Wkv; dst = Wkvb; off = i - 3145728; }
  else if (i < 3440640) { src = Wrk; dst = Wrkb; off = i - 3407872; }
  else                  { src = Wo;  dst = Wob;  off = i - 3440640; }
  float4 v = ((const float4*)src)[off];
  ushort4 o;
  o.x = f2b(v.x); o.y = f2b(v.y); o.z = f2b(v.z); o.w = f2b(v.w);
  ((ushort4*)dst)[off] = o;
}

// ================ BK=64 + T2-swizzle 128x128 GEMM core (macro-free helpers) ========
// LDS image: row-major [128][64] u16 per matrix, value at (row, cb) comes from
// global (row, cb ^ ((row&7)<<4)) [byte cols]. Stage: slot j (1KB) covers rows
// j*8..j*8+7; lane L -> row j*8+(L>>3), src col-byte ((L&7)^(L>>3))<<4.
// Read: frag row = base+i*16+r, col-byte (kk*64+hi*16) ^ ((r&7)<<4)  -> 2-way banks.

// ---------------- m97-style 128x128 tile GEMM, BK=64+swz (f32 out, for Wo) -------
__global__ __launch_bounds__(256) void gemm128(const u16* __restrict__ A,
                                               const u16* __restrict__ W,
                                               const float* __restrict__ bias,
                                               float* __restrict__ C,
                                               int M, int N, int K) {
  __shared__ u16 As[128 * 64];
  __shared__ u16 Bs[128 * 64];
  const int w = threadIdx.x >> 6, lane = threadIdx.x & 63;
  const int r = lane & 15, hi = lane >> 4, rg = hi * 4;
  const int wm = w >> 1, wn = w & 1;
  const int m0 = blockIdx.y * 128, n0 = blockIdx.x * 128;
  const int subrow = lane >> 3;                     // 0..7
  const int scb = (((lane & 7) ^ subrow) << 4);     // swizzled src col-byte
  f32x4 acc[4][4];
#pragma unroll
  for (int i = 0; i < 4; ++i)
#pragma unroll
    for (int j = 0; j < 4; ++j) acc[i][j] = (f32x4){0.f, 0.f, 0.f, 0.f};

  for (int k0 = 0; k0 < K; k0 += 64) {
#pragma unroll
    for (int i = 0; i < 4; ++i) {
      const int j = w * 4 + i;                      // slot 0..15
      gload_lds16((const char*)(A + (size_t)(m0 + j * 8 + subrow) * K + k0) + scb,
                  (char*)As + j * 1024);
      gload_lds16((const char*)(W + (size_t)(n0 + j * 8 + subrow) * K + k0) + scb,
                  (char*)Bs + j * 1024);
    }
    __syncthreads();
#pragma unroll
    for (int kk = 0; kk < 2; ++kk) {
      const int cswz = (kk * 64 + hi * 16) ^ ((r & 7) << 4);
      bf16x8 a[4], b[4];
#pragma unroll
      for (int i = 0; i < 4; ++i)
        a[i] = *(const bf16x8*)((const char*)As + (wm * 64 + i * 16 + r) * 128 + cswz);
#pragma unroll
      for (int j = 0; j < 4; ++j)
        b[j] = *(const bf16x8*)((const char*)Bs + (wn * 64 + j * 16 + r) * 128 + cswz);
#pragma unroll
      for (int i = 0; i < 4; ++i)
#pragma unroll
        for (int j = 0; j < 4; ++j)
          acc[i][j] = __builtin_amdgcn_mfma_f32_16x16x32_bf16(a[i], b[j], acc[i][j], 0, 0, 0);
    }
    __syncthreads();
  }
#pragma unroll
  for (int j = 0; j < 4; ++j) {
    const float bv = bias[n0 + wn * 64 + j * 16 + r];
#pragma unroll
    for (int i = 0; i < 4; ++i)
#pragma unroll
      for (int ii = 0; ii < 4; ++ii)
        C[(size_t)(m0 + wm * 64 + i * 16 + rg + ii) * N + n0 + wn * 64 + j * 16 + r] =
            acc[i][j][ii] + bv;
  }
}

// ---------------- fused Q GEMM, BK=64+swz: rope+scale -> bf16 granule images -----
__global__ __launch_bounds__(256) void gemm_q_fused(const u16* __restrict__ A,
                                                    const u16* __restrict__ W,
                                                    const float* __restrict__ bias,
                                                    const float* __restrict__ cosb,
                                                    const float* __restrict__ sinb,
                                                    u16* __restrict__ Qb) {
  __shared__ u16 As[128 * 64];
  __shared__ u16 Bs[128 * 64];
  const int w = threadIdx.x >> 6, lane = threadIdx.x & 63;
  const int r = lane & 15, hi = lane >> 4, rg = hi * 4;
  const int wm = w >> 1, wn = w & 1;
  const int h = blockIdx.x;
  const int m0 = blockIdx.y * 128, n0 = h * 128;
  const int subrow = lane >> 3;
  const int scb = (((lane & 7) ^ subrow) << 4);
  f32x4 acc[4][4];
#pragma unroll
  for (int i = 0; i < 4; ++i)
#pragma unroll
    for (int j = 0; j < 4; ++j) acc[i][j] = (f32x4){0.f, 0.f, 0.f, 0.f};

  for (int k0 = 0; k0 < DD; k0 += 64) {
#pragma unroll
    for (int i = 0; i < 4; ++i) {
      const int j = w * 4 + i;
      gload_lds16((const char*)(A + (size_t)(m0 + j * 8 + subrow) * DD + k0) + scb,
                  (char*)As + j * 1024);
      gload_lds16((const char*)(W + (size_t)(n0 + j * 8 + subrow) * DD + k0) + scb,
                  (char*)Bs + j * 1024);
    }
    __syncthreads();
#pragma unroll
    for (int kk = 0; kk < 2; ++kk) {
      const int cswz = (kk * 64 + hi * 16) ^ ((r & 7) << 4);
      bf16x8 a[4], b[4];
#pragma unroll
      for (int i = 0; i < 4; ++i)
        a[i] = *(const bf16x8*)((const char*)As + (wm * 64 + i * 16 + r) * 128 + cswz);
#pragma unroll
      for (int j = 0; j < 4; ++j)
        b[j] = *(const bf16x8*)((const char*)Bs + (wn * 64 + j * 16 + r) * 128 + cswz);
#pragma unroll
      for (int i = 0; i < 4; ++i)
#pragma unroll
        for (int j = 0; j < 4; ++j)
          acc[i][j] = __builtin_amdgcn_mfma_f32_16x16x32_bf16(a[i], b[j], acc[i][j], 0, 0, 0);
    }
    __syncthreads();
  }

  const int b = m0 >> 11;
  const int lbase = (m0 & 2047) + wm * 64;
  u16* Qimg = Qb + (size_t)((b * 16 + h) * 128) * 2048;
  if (wn == 0) {
#pragma unroll
    for (int j = 0; j < 4; ++j) {
      const int d = j * 16 + r;                     // < 64: no rope
      const float bv = bias[h * 128 + d];
#pragma unroll
      for (int i = 0; i < 4; ++i)
#pragma unroll
        for (int ii = 0; ii < 4; ++ii) {
          const int l = lbase + i * 16 + rg + ii;
          Qimg[(size_t)(l >> 4) * 2048 + (d >> 5) * 512 + ((d >> 3) & 3) * 128 +
               (l & 15) * 8 + (d & 7)] = f2b((acc[i][j][ii] + bv) * QSCALE);
        }
    }
  } else {
#pragma unroll
    for (int jp = 0; jp < 2; ++jp) {
      const int dd0 = jp * 16 + r;                  // 0..31
      const int dd1 = dd0 + 32;                     // 32..63
      const float bv0 = bias[h * 128 + 64 + dd0];
      const float bv1 = bias[h * 128 + 64 + dd1];
#pragma unroll
      for (int i = 0; i < 4; ++i)
#pragma unroll
        for (int ii = 0; ii < 4; ++ii) {
          const int l = lbase + i * 16 + rg + ii;
          const size_t nb = (size_t)(b * 2048 + l) * 64;
          const float c0 = cosb[nb + dd0], s0 = sinb[nb + dd0];
          const float c1 = cosb[nb + dd1], s1 = sinb[nb + dd1];
          const float a0 = acc[i][jp][ii] + bv0;
          const float a1 = acc[i][jp + 2][ii] + bv1;
          const float v0 = (a0 * c0 - a1 * s0) * QSCALE;
          const float v1 = (a1 * c1 + a0 * s1) * QSCALE;
          const int d0f = 64 + dd0, d1f = 64 + dd1;
          const size_t rowoff = (size_t)(l >> 4) * 2048 + (l & 15) * 8;
          Qimg[rowoff + (d0f >> 5) * 512 + ((d0f >> 3) & 3) * 128 + (d0f & 7)] = f2b(v0);
          Qimg[rowoff + (d1f >> 5) * 512 + ((d1f >> 3) & 3) * 128 + (d1f & 7)] = f2b(v1);
        }
    }
  }
}

// ---------------- fused KV GEMM, BK=64+swz -> 64-key-tile K-tied + interleaved-V ----
__global__ __launch_bounds__(256) void gemm_kv_fused(const u16* __restrict__ A,
                                                     const u16* __restrict__ W,
                                                     const float* __restrict__ bias,
                                                     u16* __restrict__ Kb,
                                                     u16* __restrict__ VTb) {
  __shared__ u16 As[128 * 64];
  __shared__ u16 Bs[128 * 64];
  const int w = threadIdx.x >> 6, lane = threadIdx.x & 63;
  const int r = lane & 15, hi = lane >> 4, rg = hi * 4;
  const int wm = w >> 1, wn = w & 1;
  const int c = blockIdx.x;
  const int m0 = blockIdx.y * 128, n0 = c * 128;
  const int subrow = lane >> 3;
  const int scb = (((lane & 7) ^ subrow) << 4);
  f32x4 acc[4][4];
#pragma unroll
  for (int i = 0; i < 4; ++i)
#pragma unroll
    for (int j = 0; j < 4; ++j) acc[i][j] = (f32x4){0.f, 0.f, 0.f, 0.f};

  for (int k0 = 0; k0 < DD; k0 += 64) {
#pragma unroll
    for (int i = 0; i < 4; ++i) {
      const int j = w * 4 + i;
      gload_lds16((const char*)(A + (size_t)(m0 + j * 8 + subrow) * DD + k0) + scb,
                  (char*)As + j * 1024);
      gload_lds16((const char*)(W + (size_t)(n0 + j * 8 + subrow) * DD + k0) + scb,
                  (char*)Bs + j * 1024);
    }
    __syncthreads();
#pragma unroll
    for (int kk = 0; kk < 2; ++kk) {
      const int cswz = (kk * 64 + hi * 16) ^ ((r & 7) << 4);
      bf16x8 a[4], b[4];
#pragma unroll
      for (int i = 0; i < 4; ++i)
        a[i] = *(const bf16x8*)((const char*)As + (wm * 64 + i * 16 + r) * 128 + cswz);
#pragma unroll
      for (int j = 0; j < 4; ++j)
        b[j] = *(const bf16x8*)((const char*)Bs + (wn * 64 + j * 16 + r) * 128 + cswz);
#pragma unroll
      for (int i = 0; i < 4; ++i)
#pragma unroll
        for (int j = 0; j < 4; ++j)
          acc[i][j] = __builtin_amdgcn_mfma_f32_16x16x32_bf16(a[i], b[j], acc[i][j], 0, 0, 0);
    }
    __syncthreads();
  }

  const int b = m0 >> 11;
  const int lbase = (m0 & 2047) + wm * 64;
  u16* Kimg = Kb + (size_t)(b * KVH + c) * 32 * 8192;
  u16* Vimg = VTb + (size_t)(b * KVH + c) * 32 * 8192;
#pragma unroll
  for (int j = 0; j < 4; ++j) {
    const int d = wn * 64 + j * 16 + r;             // 0..127
    const float bv = bias[c * 128 + d];
#pragma unroll
    for (int i = 0; i < 4; ++i)
#pragma unroll
      for (int ii = 0; ii < 4; ++ii) {
        const int l = lbase + i * 16 + rg + ii;     // key
        const u16 bf = f2b(acc[i][j][ii] + bv);
        const int lt = l & 63;
        Vimg[(size_t)(l >> 6) * 8192 + ((d >> 4) * 2 + ((lt >> 5) & 1)) * 512 +
             ((lt >> 2) & 3) * 128 + (d & 15) * 8 + ((lt >> 4) & 1) * 4 + (lt & 3)] = bf;
        if (wn == 0)
          Kimg[(size_t)(l >> 6) * 8192 + ((lt >> 4) & 3) * 2048 + (d >> 5) * 512 +
               ((d >> 3) & 3) * 128 + (lt & 15) * 8 + (d & 7)] = bf;
      }
  }
}

// ---------------- fused RK GEMM: k_rope = x@Wrk^T + brk, rope, -> K-image d>=64 ----
__global__ __launch_bounds__(256) void gemm_rk_fused(const u16* __restrict__ A,
                                                     const u16* __restrict__ Wrkb,
                                                     const float* __restrict__ brk,
                                                     const float* __restrict__ cosb,
                                                     const float* __restrict__ sinb,
                                                     u16* __restrict__ Kb) {
  __shared__ f32x4 red[4][2][64];
  const int w = threadIdx.x >> 6, lane = threadIdx.x & 63;
  const int bx = blockIdx.x;                        // 0..1
  const int m0 = blockIdx.y * 16;
  const int r = lane & 15;
  const int kq = (lane >> 4) * 8;
  const u16* ap  = A + (size_t)(m0 + r) * DD + kq;
  const u16* wp0 = Wrkb + (size_t)(bx * 16 + r) * DD + kq;
  const u16* wp1 = Wrkb + (size_t)(bx * 16 + 32 + r) * DD + kq;
  f32x4 acc0 = {0.f, 0.f, 0.f, 0.f}, acc1 = {0.f, 0.f, 0.f, 0.f};
  for (int k = w * 512; k < w * 512 + 512; k += 32) {
    bf16x8 a  = *(const bf16x8*)(ap + k);
    bf16x8 b0 = *(const bf16x8*)(wp0 + k);
    bf16x8 b1 = *(const bf16x8*)(wp1 + k);
    acc0 = __builtin_amdgcn_mfma_f32_16x16x32_bf16(a, b0, acc0, 0, 0, 0);
    acc1 = __builtin_amdgcn_mfma_f32_16x16x32_bf16(a, b1, acc1, 0, 0, 0);
  }
  red[w][0][lane] = acc0;
  red[w][1][lane] = acc1;
  __syncthreads();
  if (w == 0) {
#pragma unroll
    for (int ww = 1; ww < 4; ++ww) {
      acc0 += red[ww][0][lane];
      acc1 += red[ww][1][lane];
    }
    const int rg = (lane >> 4) * 4;
    const int dd0 = bx * 16 + r, dd1 = dd0 + 32;
    const float bv0 = brk[dd0], bv1 = brk[dd1];
    const int d0f = 64 + dd0, d1f = 64 + dd1;
#pragma unroll
    for (int i = 0; i < 4; ++i) {
      const int n = m0 + rg + i;                    // global row
      const int b = n >> 11, l = n & 2047;
      const size_t nb = (size_t)n * 64;
      const float c0 = cosb[nb + dd0], s0 = sinb[nb + dd0];
      const float c1 = cosb[nb + dd1], s1 = sinb[nb + dd1];
      const float a0 = acc0[i] + bv0;
      const float a1 = acc1[i] + bv1;
      const u16 v0 = f2b(a0 * c0 - a1 * s0);        // K col 64+dd0
      const u16 v1 = f2b(a1 * c1 + a0 * s1);        // K col 64+dd1
      const int lt = l & 63;
      const size_t loff = (size_t)(l >> 6) * 8192 + ((lt >> 4) & 3) * 2048 + (lt & 15) * 8;
#pragma unroll
      for (int c = 0; c < 4; ++c) {
        u16* Kimg = Kb + (size_t)(b * KVH + c) * 32 * 8192;
        Kimg[loff + (d0f >> 5) * 512 + ((d0f >> 3) & 3) * 128 + (d0f & 7)] = v0;
        Kimg[loff + (d1f >> 5) * 512 + ((d1f >> 3) & 3) * 128 + (d1f & 7)] = v1;
      }
    }
  }
}

// ---------------- stage one 64-key tile for a 4-wave group ----------------
static __device__ __forceinline__ void stage_g(const u16* Kt, const u16* Vt,
                                               char* GB, int buf, int wg, int lane) {
#pragma unroll
  for (int i = 0; i < 4; ++i) {
    const int j = wg * 4 + i;                       // slot 0..15
    gload_lds16(Kt + (size_t)j * 512 + lane * 8, (u16*)(GB + buf * 16384) + j * 512);
    gload_lds16(Vt + (size_t)j * 512 + lane * 8, (u16*)(GB + 32768 + buf * 16384) + j * 512);
  }
}

// ---------------- MFMA flash attention v10: intra-block split-K, uniform blocks ----------------
__global__ __launch_bounds__(512, 2) void attn_mfma10(const u16* __restrict__ Qb,
                                                      const u16* __restrict__ Kb,
                                                      const u16* __restrict__ VTb,
                                                      u16* __restrict__ attn_bf) {
  const int id = blockIdx.x;
  const int g = id & 31;
  const int s = id >> 5;                            // 0..7
  const int bc = g & 7, hlow = g >> 3;              // id%8 == bc -> XCD clustering
  const int b = bc >> 2, c = bc & 3;
  const int h = c * 4 + hlow;
  const int bh = b * 16 + h;
  const int w = threadIdx.x >> 6, lane = threadIdx.x & 63;
  const int r = lane & 15, hi = lane >> 4, rg = hi * 4;
  const int grp = w >> 2, wg = w & 3;

  __shared__ __align__(16) char LB[131072];         // 2 groups x (K dbuf 32KB + V dbuf 32KB)
  char* GB = LB + grp * 65536;

  const u16* Ktg = Kb + (size_t)(b * KVH + c) * 32 * 8192;
  const u16* Vtg = VTb + (size_t)(b * KVH + c) * 32 * 8192;

  for (int ss = 0; ss < 2; ++ss) {
    const int qb = ss ? s : (15 - s);
    const int q0 = qb * 128 + wg * 32;              // this wave's 32 q rows
    const int half = qb + 1;                        // tiles per group (nt=2qb+2 even)
    const int tb = grp ? half : 0;                  // group's first tile

    bf16x8 qf[2][4];
#pragma unroll
    for (int qs = 0; qs < 2; ++qs) {
      const u16* qtb = Qb + (size_t)(bh * 128 + qb * 8 + wg * 2 + qs) * 2048;
#pragma unroll
      for (int ks = 0; ks < 4; ++ks)
        qf[qs][ks] = *(const bf16x8*)(qtb + ks * 512 + lane * 8);
    }

    float m_[2] = {-3.0e38f, -3.0e38f}, l_[2] = {0.f, 0.f};
    f32x4 o[2][8];
#pragma unroll
    for (int qs = 0; qs < 2; ++qs)
#pragma unroll
      for (int t = 0; t < 8; ++t) o[qs][t] = (f32x4){0.f, 0.f, 0.f, 0.f};

    stage_g(Ktg + (size_t)tb * 8192, Vtg + (size_t)tb * 8192, GB, 0, wg, lane);
    __syncthreads();
    int cur = 0;

    for (int t = 0; t < half; ++t) {
      if (t + 1 < half)
        stage_g(Ktg + (size_t)(tb + t + 1) * 8192, Vtg + (size_t)(tb + t + 1) * 8192,
                GB, cur ^ 1, wg, lane);
      const int s0 = (tb + t) * 64;

      if (s0 <= q0 + 31) {                          // wave-uniform skip (group B early q)
        const u16* Kl = (const u16*)(GB + cur * 16384);
        const u16* Vl = (const u16*)(GB + 32768 + cur * 16384);

        f32x4 st[2][4];
#pragma unroll
        for (int qs = 0; qs < 2; ++qs)
#pragma unroll
          for (int tt = 0; tt < 4; ++tt) st[qs][tt] = (f32x4){0.f, 0.f, 0.f, 0.f};
        __builtin_amdgcn_s_setprio(1);
#pragma unroll
        for (int tt = 0; tt < 4; ++tt) {
          bf16x8 kf[4];
#pragma unroll
          for (int ks = 0; ks < 4; ++ks)
            kf[ks] = *(const bf16x8*)(Kl + tt * 2048 + ks * 512 + lane * 8);
#pragma unroll
          for (int qs = 0; qs < 2; ++qs)
#pragma unroll
            for (int ks = 0; ks < 4; ++ks)
              st[qs][tt] = __builtin_amdgcn_mfma_f32_16x16x32_bf16(kf[ks], qf[qs][ks], st[qs][tt], 0, 0, 0);
        }
        __builtin_amdgcn_s_setprio(0);

        if (s0 + 63 > q0) {
#pragma unroll
          for (int qs = 0; qs < 2; ++qs)
#pragma unroll
            for (int tt = 0; tt < 4; ++tt)
#pragma unroll
              for (int i = 0; i < 4; ++i)
                if (s0 + tt * 16 + rg + i > q0 + qs * 16 + r) st[qs][tt][i] = -3.0e38f;
        }

        float vmax[2];
#pragma unroll
        for (int qs = 0; qs < 2; ++qs) {
          float v = st[qs][0][0];
#pragma unroll
          for (int tt = 0; tt < 4; ++tt)
#pragma unroll
            for (int i = 0; i < 4; ++i) v = fmaxf(v, st[qs][tt][i]);
          v = fmaxf(v, __shfl_xor(v, 16));
          v = fmaxf(v, __shfl_xor(v, 32));
          vmax[qs] = v;
        }
        const float grow = fmaxf(vmax[0] - m_[0], vmax[1] - m_[1]);
        if (!__all(grow <= 11.54f)) {
#pragma unroll
          for (int qs = 0; qs < 2; ++qs) {
            const float mn = fmaxf(m_[qs], vmax[qs]);
            const float cf = exp2f(m_[qs] - mn);
            l_[qs] *= cf;
            m_[qs] = mn;
#pragma unroll
            for (int tt = 0; tt < 8; ++tt)
#pragma unroll
              for (int i = 0; i < 4; ++i) o[qs][tt][i] *= cf;
          }
        }
        bf16x8 pa[2][2];
#pragma unroll
        for (int qs = 0; qs < 2; ++qs) {
          float ps = 0.f;
#pragma unroll
          for (int tt = 0; tt < 4; ++tt)
#pragma unroll
            for (int i = 0; i < 4; ++i) {
              st[qs][tt][i] = exp2f(st[qs][tt][i] - m_[qs]);
              ps += st[qs][tt][i];
            }
          ps += __shfl_xor(ps, 16);
          ps += __shfl_xor(ps, 32);
          l_[qs] += ps;
#pragma unroll
          for (int kb = 0; kb < 2; ++kb) {
            bf16x8 v;
#pragma unroll
            for (int jj = 0; jj < 8; ++jj)
              v[jj] = (short)f2b(st[qs][2 * kb + (jj >> 2)][jj & 3]);
            pa[qs][kb] = v;
          }
        }

        __builtin_amdgcn_s_setprio(1);
#pragma unroll
        for (int tt = 0; tt < 8; ++tt) {
#pragma unroll
          for (int kb = 0; kb < 2; ++kb) {
            bf16x8 vf = *(const bf16x8*)(Vl + tt * 1024 + kb * 512 + lane * 8);
#pragma unroll
            for (int qs = 0; qs < 2; ++qs)
              o[qs][tt] = __builtin_amdgcn_mfma_f32_16x16x32_bf16(pa[qs][kb], vf, o[qs][tt], 0, 0, 0);
          }
        }
        __builtin_amdgcn_s_setprio(0);
      }

      __syncthreads();
      cur ^= 1;
    }

    // ---- split-K combine ----
    float2* mlp = (float2*)(LB + 65536);
    if (hi == 0) {
      mlp[(w * 2 + 0) * 16 + r] = make_float2(m_[0], l_[0]);
      mlp[(w * 2 + 1) * 16 + r] = make_float2(m_[1], l_[1]);
    }
    __syncthreads();
    float lC[2], asc[2];
#pragma unroll
    for (int qs = 0; qs < 2; ++qs) {
      const float2 p = mlp[((w ^ 4) * 2 + qs) * 16 + r];
      const float mn = fmaxf(m_[qs], p.x);
      const float a1 = exp2f(m_[qs] - mn);
      lC[qs] = l_[qs] * a1 + p.y * exp2f(p.x - mn);
      asc[qs] = a1;
    }
#pragma unroll
    for (int qs = 0; qs < 2; ++qs) {
      float ai[4];
#pragma unroll
      for (int i = 0; i < 4; ++i) ai[i] = __shfl(asc[qs], (lane & 48) + rg + i);
#pragma unroll
      for (int tt = 0; tt < 8; ++tt)
#pragma unroll
        for (int i = 0; i < 4; ++i) o[qs][tt][i] *= ai[i];
    }
    if (grp == 1) {
#pragma unroll
      for (int qs = 0; qs < 2; ++qs)
#pragma unroll
        for (int tt = 0; tt < 8; ++tt)
          *(f32x4*)(LB + wg * 16384 + (qs * 8 + tt) * 1024 + lane * 16) = o[qs][tt];
    }
    __syncthreads();
    if (grp == 0) {
#pragma unroll
      for (int qs = 0; qs < 2; ++qs) {
#pragma unroll
        for (int tt = 0; tt < 8; ++tt)
          o[qs][tt] += *(const f32x4*)(LB + wg * 16384 + (qs * 8 + tt) * 1024 + lane * 16);
        const float il = 1.f / lC[qs];
        float inv[4];
#pragma unroll
        for (int i = 0; i < 4; ++i) inv[i] = __shfl(il, (lane & 48) + rg + i);
        u16* op = attn_bf + (size_t)(b * LL + q0 + qs * 16 + rg) * DD + h * HDD;
#pragma unroll
        for (int tt = 0; tt < 8; ++tt)
#pragma unroll
          for (int i = 0; i < 4; ++i)
            op[(size_t)i * DD + tt * 16 + r] = f2b(o[qs][tt][i] * inv[i]);
      }
    }
    __syncthreads();
  }
}

extern "C" void kernel_launch(void* const* d_in, const int* in_sizes, int n_in,
                              void* d_out, int out_size, void* d_ws, size_t ws_size,
                              hipStream_t stream) {
  const float* x    = (const float*)d_in[0];
  const float* cosb = (const float*)d_in[1];
  const float* sinb = (const float*)d_in[2];
  const float* Wq   = (const float*)d_in[3];
  const float* bq   = (const float*)d_in[4];
  const float* Wkv  = (const float*)d_in[5];
  const float* bkv  = (const float*)d_in[6];
  const float* Wrk  = (const float*)d_in[7];
  const float* brk  = (const float*)d_in[8];
  const float* Wo   = (const float*)d_in[9];
  const float* bo   = (const float*)d_in[10];
  float* out = (float*)d_out;

  // Workspace layout (78,905,344 B total):
  char* ws = (char*)d_ws;
  u16*   Qb    = (u16*)(ws);                        // 16,777,216
  u16*   attn_bf = (u16*)(ws + 16777216);           // 16,777,216
  u16*   xb    = (u16*)(ws + 33554432);             // 16,777,216
  u16*   Wqb   = (u16*)(ws + 50331648);             //  8,388,608
  u16*   Wob   = (u16*)(ws + 58720256);             //  8,388,608
  u16*   Wkvb  = (u16*)(ws + 67108864);             //  2,097,152
  u16*   Wrkb  = (u16*)(ws + 69206016);             //    262,144
  u16*   Kb    = (u16*)(ws + 70516736);             //  4,194,304
  u16*   VTb   = (u16*)(ws + 74711040);             //  4,194,304 -> 78,905,344

  // 1) all casts in one kernel (4,489,216 float4 / 256 = 17,536 blocks)
  cast_all<<<17536, 256, 0, stream>>>(x, Wq, Wkv, Wrk, Wo, xb, Wqb, Wkvb, Wrkb, Wob);

  // 2) fused projections -> attention operand images (no f32 intermediates)
  gemm_q_fused<<<dim3(HH, MM / 128), 256, 0, stream>>>(xb, Wqb, bq, cosb, sinb, Qb);
  gemm_kv_fused<<<dim3(KVH, MM / 128), 256, 0, stream>>>(xb, Wkvb, bkv, Kb, VTb);
  gemm_rk_fused<<<dim3(2, MM / 16), 256, 0, stream>>>(xb, Wrkb, brk, cosb, sinb, Kb);

  // 3) MFMA flash attention v10 -> bf16
  attn_mfma10<<<dim3(256), 512, 0, stream>>>(Qb, Kb, VTb, attn_bf);

  // 4) output projection -> d_out (f32), BK=64 + T2 swizzle
  gemm128<<<dim3(DD / 128, MM / 128), 256, 0, stream>>>(attn_bf, Wob, bo, out, MM, DD, DD);
}